// Round 4
// baseline (311.907 us; speedup 1.0000x reference)
//
#include <hip/hip_runtime.h>

// BaseModel_3100966387783 — per-variable masked 3-layer MLP, b=8192, D=128, h=64, o=2.
//
// R7: occupancy round. R6 counters showed VGPR_Count=120 (compiler REJECTED
//   weight residency; re-loads weights from L2 per s-iter) and fused_mlp =
//   42.6 us real. At 120 VGPR the HW supports 4 waves/SIMD, but R6's 512-block
//   grid only supplied 2 blocks/CU. Fix: grid (8,128) = 1024 blocks = 4
//   blocks/CU, 8 s-iters, __launch_bounds__(256,4) pins VGPR<=128 (no spill
//   expected from 120). Latency (L2 weight reloads + DS round-trip) now hidden
//   by 4 waves/SIMD instead of 2.
//   Prediction: fused 42.6 -> 22-28 us; dur_us 109.7 -> 88-96 us.
//
// R6 (109.7 us): 512 blocks x 16 iters; per-ntl L1+finish split (acc1[4]).
// R5 (107.9 us): layer-2 as in-register VALU finish (no 2nd LDS round-trip).
// R3/R4 (105.7-107.4 us): brick layout, 0 barriers.
//   brick = 1 KB = 64 lanes x 16 B bf16; lane l holds
//   T[tile*16 + (l&15)][ks*32 + (l>>4)*8 + 0..7] = one MFMA A/B fragment.

typedef __bf16 bf16_t;
typedef __bf16 bf16x8 __attribute__((ext_vector_type(8)));
typedef float  f32x4  __attribute__((ext_vector_type(4)));

#define LEAKY 0.01f

// ---------------- ws brick regions (byte offsets) ----------------
#define XB_OFF   0u                  // x bricks:   64 bt x 8 nt x 4 ks = 2048 bricks
#define W0B_OFF  (2048u*1024u)       // w0 masked: 128 t x 4 it x 4 ks = 2048
#define W1B_OFF  (4096u*1024u)       // w1:        128 t x 4 it x 2 ks = 1024
// total ws need: 5120 KiB (w2 read as fp32 directly in fused_mlp)

// =================== pre-kernel: fp32 -> bf16 brick-ify ===================
__global__ __launch_bounds__(256)
void brickify(const float* __restrict__ x,  const float* __restrict__ w0,
              const float* __restrict__ w1, unsigned char* __restrict__ ws)
{
    const int wid  = blockIdx.x * 4 + (threadIdx.x >> 6);  // one wave = one brick
    const int lane = threadIdx.x & 63;
    const int lr = lane & 15, lq = lane >> 4;

    float v[8];
    if (wid < 2048) {                        // ---- x bricks ----
        int bt = wid >> 5, rem = wid & 31, nt = rem >> 2, ks = rem & 3;
        const float* s = x + (size_t)(bt*128 + nt*16 + lr) * 128 + ks*32 + lq*8;
        const float4 a = *(const float4*)s, b = *(const float4*)(s + 4);
        v[0]=a.x; v[1]=a.y; v[2]=a.z; v[3]=a.w;
        v[4]=b.x; v[5]=b.y; v[6]=b.z; v[7]=b.w;
    } else if (wid < 4096) {                 // ---- w0 bricks (masked) ----
        int u = wid - 2048, t = u >> 4, rem = u & 15, it = rem >> 2, ks = rem & 3;
        int k0 = ks*32 + lq*8;
        const float* s = w0 + (size_t)(t*64 + it*16 + lr) * 128 + k0;
        const float4 a = *(const float4*)s, b = *(const float4*)(s + 4);
        v[0]=a.x; v[1]=a.y; v[2]=a.z; v[3]=a.w;
        v[4]=b.x; v[5]=b.y; v[6]=b.z; v[7]=b.w;
        #pragma unroll
        for (int j = 0; j < 8; ++j) if (k0 + j == t) v[j] = 0.f;
    } else {                                 // ---- w1 bricks ----
        int u = wid - 4096, t = u >> 3, rem = u & 7, it = rem >> 1, ks = rem & 1;
        const float* s = w1 + (size_t)(t*64 + it*16 + lr) * 64 + ks*32 + lq*8;
        const float4 a = *(const float4*)s, b = *(const float4*)(s + 4);
        v[0]=a.x; v[1]=a.y; v[2]=a.z; v[3]=a.w;
        v[4]=b.x; v[5]=b.y; v[6]=b.z; v[7]=b.w;
    }
    union { bf16_t h[8]; uint4 q; } pk;
    #pragma unroll
    for (int j = 0; j < 8; ++j) pk.h[j] = (bf16_t)v[j];
    ((uint4*)ws)[(size_t)wid * 64 + lane] = pk.q;   // dst = brick*1024 + lane*16
}

// =========================== main fused kernel ===========================
__global__ __launch_bounds__(256, 4)
void fused_mlp(const unsigned char* __restrict__ ws,
               const float* __restrict__ w2,
               const float* __restrict__ b0, const float* __restrict__ b1,
               const float* __restrict__ b2, float* __restrict__ out)
{
    // h bricks only: 8 nt-tiles x 2 ks = 16 bricks, wave-private slices. No barriers.
    __shared__ __align__(16) unsigned char hsm[16384];

    const int tid  = threadIdx.x;
    const int w    = tid >> 6;         // wave 0..3: owns batch rows w*32 .. w*32+31
    const int lane = tid & 63;
    const int lr = lane & 15, lq = lane >> 4;
    const int g  = blockIdx.x;         // batch group: bt = g*8 + s
    const int t  = blockIdx.y;         // variable index

    // ---- weight fragment pointers (compiler chooses reload-vs-resident) ----
    const unsigned char* w0p = ws + W0B_OFF + (size_t)t*16384 + lane*16;
    const unsigned char* w1p = ws + W1B_OFF + (size_t)t*8192  + lane*16;
    bf16x8 w0f[4][4], w1f[4][2];
    #pragma unroll
    for (int it = 0; it < 4; ++it)
        #pragma unroll
        for (int ks = 0; ks < 4; ++ks)
            w0f[it][ks] = *(const bf16x8*)(w0p + (it*4+ks)*1024);
    #pragma unroll
    for (int it = 0; it < 4; ++it)
        #pragma unroll
        for (int ks = 0; ks < 2; ++ks)
            w1f[it][ks] = *(const bf16x8*)(w1p + (it*2+ks)*1024);

    // ---- w2 as fp32, per-lane slice for the in-register L2 finish ----
    f32x4 w2q[2][4];
    #pragma unroll
    for (int o = 0; o < 2; ++o)
        #pragma unroll
        for (int it = 0; it < 4; ++it)
            w2q[o][it] = *(const f32x4*)(w2 + t*128 + o*64 + it*16 + lq*4);

    // ---- biases: per-quad float4 (acc-init form) ----
    f32x4 b0q[4], b1q[4];
    #pragma unroll
    for (int it = 0; it < 4; ++it) {
        b0q[it] = *(const f32x4*)(b0 + t*64 + it*16 + lq*4);
        b1q[it] = *(const f32x4*)(b1 + t*64 + it*16 + lq*4);
    }
    const float2 b2v = *(const float2*)(b2 + t*2);

    // ---- x fragment pointer helper; preload iter 0 ----
    const unsigned char* xp = ws + XB_OFF + lane*16;
    bf16x8 xf[2][4];
    {
        const int bt0 = g*8;
        #pragma unroll
        for (int ntl = 0; ntl < 2; ++ntl)
            #pragma unroll
            for (int ks = 0; ks < 4; ++ks)
                xf[ntl][ks] = *(const bf16x8*)(xp + (size_t)(((bt0*8 + w*2+ntl)*4 + ks))*1024);
    }

    for (int s = 0; s < 8; ++s) {
        const int bt = g*8 + s;

        // ============ layer 0: D0[i][row] = w0m @ x^T (+b0 via C-init) ============
        f32x4 acc0[2][4];
        #pragma unroll
        for (int ntl = 0; ntl < 2; ++ntl)
            #pragma unroll
            for (int it = 0; it < 4; ++it) acc0[ntl][it] = b0q[it];

        #pragma unroll
        for (int ks = 0; ks < 4; ++ks)
            #pragma unroll
            for (int it = 0; it < 4; ++it)
                #pragma unroll
                for (int ntl = 0; ntl < 2; ++ntl)
                    acc0[ntl][it] = __builtin_amdgcn_mfma_f32_16x16x32_bf16(
                                        w0f[it][ks], xf[ntl][ks], acc0[ntl][it], 0, 0, 0);

        // ---- xf now dead: prefetch next iter's fragments into the same regs ----
        {
            const int btn = (s < 7) ? bt + 1 : bt;
            #pragma unroll
            for (int ntl = 0; ntl < 2; ++ntl)
                #pragma unroll
                for (int ks = 0; ks < 4; ++ks)
                    xf[ntl][ks] = *(const bf16x8*)(xp + (size_t)(((btn*8 + w*2+ntl)*4 + ks))*1024);
        }

        // epi0 -> h bricks: C reg r is k = it*16 + lq*4 + r (4 consecutive k) -> one b64
        #pragma unroll
        for (int ntl = 0; ntl < 2; ++ntl)
            #pragma unroll
            for (int it = 0; it < 4; ++it) {
                union { bf16_t h[4]; unsigned long long u; } pk;
                #pragma unroll
                for (int r = 0; r < 4; ++r) {
                    float u = acc0[ntl][it][r];
                    pk.h[r] = (bf16_t)fmaxf(u, LEAKY * u);
                }
                int off = ((w*2+ntl)*2 + (it>>1)) * 1024
                        + (((it&1)*2 + (lq>>1))*16 + lr) * 16 + (lq&1)*8;
                *(unsigned long long*)(hsm + off) = pk.u;
            }

        // ============ layers 1+2, per-ntl (halves acc1 register pressure) ============
        #pragma unroll
        for (int ntl = 0; ntl < 2; ++ntl) {
            bf16x8 hf[2];
            #pragma unroll
            for (int ks = 0; ks < 2; ++ks)
                hf[ks] = *(const bf16x8*)(hsm + ((w*2+ntl)*2 + ks)*1024 + lane*16);

            f32x4 acc1[4];
            #pragma unroll
            for (int it = 0; it < 4; ++it) acc1[it] = b1q[it];

            #pragma unroll
            for (int ks = 0; ks < 2; ++ks)
                #pragma unroll
                for (int it = 0; it < 4; ++it)
                    acc1[it] = __builtin_amdgcn_mfma_f32_16x16x32_bf16(
                                   w1f[it][ks], hf[ks], acc1[it], 0, 0, 0);

            // layer 2 (o=2) — in-register VALU finish:
            // out[o][row] = sum_i2 w2[o][i2] * leaky(acc1[i2][row]) + b2[o]
            float p0 = 0.f, p1 = 0.f;
            #pragma unroll
            for (int it = 0; it < 4; ++it)
                #pragma unroll
                for (int r = 0; r < 4; ++r) {
                    float u = acc1[it][r];
                    float a = fmaxf(u, LEAKY * u);
                    p0 = fmaf(w2q[0][it][r], a, p0);
                    p1 = fmaf(w2q[1][it][r], a, p1);
                }
            p0 += __shfl_xor(p0, 16); p0 += __shfl_xor(p0, 32);
            p1 += __shfl_xor(p1, 16); p1 += __shfl_xor(p1, 32);
            if (lq == 0) {
                int row = bt*128 + (w*2+ntl)*16 + lr;
                float2 o2 = { p0 + b2v.x, p1 + b2v.y };
                *(float2*)(out + (size_t)row*256 + t*2) = o2;
            }
        }
    }
}

extern "C" void kernel_launch(void* const* d_in, const int* in_sizes, int n_in,
                              void* d_out, int out_size, void* d_ws, size_t ws_size,
                              hipStream_t stream) {
    const float* x  = (const float*)d_in[0];
    const float* w0 = (const float*)d_in[1];
    const float* w1 = (const float*)d_in[2];
    const float* w2 = (const float*)d_in[3];
    const float* b0 = (const float*)d_in[4];
    const float* b1 = (const float*)d_in[5];
    const float* b2 = (const float*)d_in[6];
    unsigned char* ws = (unsigned char*)d_ws;   // needs 5120 KiB
    float* out = (float*)d_out;

    brickify<<<dim3(1280), dim3(256), 0, stream>>>(x, w0, w1, ws);
    // grid (8 batch-groups, 128 t): 1024 blocks = 4 blocks/CU (VGPR<=128,
    // LDS 16KB -> not limiting). XCD = blockid%8 = g: each XCD sees one
    // group's x bricks (256 KB) + all weights (3 MB) -> fits 4 MB L2.
    fused_mlp<<<dim3(8, 128), dim3(256), 0, stream>>>(ws, w2, b0, b1, b2, out);
}

// Round 5
// 107.899 us; speedup vs baseline: 2.8907x; 2.8907x over previous
//
#include <hip/hip_runtime.h>

// BaseModel_3100966387783 — per-variable masked 3-layer MLP, b=8192, D=128, h=64, o=2.
//
// R8: weights L2 -> LDS. R7's forced-occupancy experiment (launch_bounds(256,4))
//   spilled to scratch (VGPR 64, FETCH 748 MB, 245 us) — reverted. R6 counters
//   showed the real steady-state: VGPR=120, compiler re-loads all 24 weight
//   fragments from L2 EVERY s-iter (~786 MB of L2 traffic, ~20-25 us + latency).
//   Fix: stage w0+w1 (24 KB) into LDS once per block (cooperative uint4 copy +
//   one barrier), read fragments per-iter via ds_read_b128 (brick layout =
//   lane*16, the proven conflict-free pattern). Grid/launch_bounds/register
//   plan otherwise identical to R6 for A/B.
//   Prediction: fused 42.6 -> 20-28 us; dur_us 109.7 -> 85-95; no spill.
//
// R7 (311.9 us): launch_bounds(256,4) -> 64 VGPR scratch-spill disaster. Reverted.
// R6 (109.7 us): 512 blocks x 16 iters; per-ntl L1+finish split; VGPR=120.
// R5 (107.9 us): layer-2 as in-register VALU finish (no 2nd LDS round-trip).
// R3/R4 (105.7-107.4 us): brick layout, 0 barriers.
//   brick = 1 KB = 64 lanes x 16 B bf16; lane l holds
//   T[tile*16 + (l&15)][ks*32 + (l>>4)*8 + 0..7] = one MFMA A/B fragment.

typedef __bf16 bf16_t;
typedef __bf16 bf16x8 __attribute__((ext_vector_type(8)));
typedef float  f32x4  __attribute__((ext_vector_type(4)));

#define LEAKY 0.01f

// ---------------- ws brick regions (byte offsets) ----------------
#define XB_OFF   0u                  // x bricks:   64 bt x 8 nt x 4 ks = 2048 bricks
#define W0B_OFF  (2048u*1024u)       // w0 masked: 128 t x 4 it x 4 ks = 2048
#define W1B_OFF  (4096u*1024u)       // w1:        128 t x 4 it x 2 ks = 1024
// total ws need: 5120 KiB (w2 read as fp32 directly in fused_mlp)

// =================== pre-kernel: fp32 -> bf16 brick-ify ===================
__global__ __launch_bounds__(256)
void brickify(const float* __restrict__ x,  const float* __restrict__ w0,
              const float* __restrict__ w1, unsigned char* __restrict__ ws)
{
    const int wid  = blockIdx.x * 4 + (threadIdx.x >> 6);  // one wave = one brick
    const int lane = threadIdx.x & 63;
    const int lr = lane & 15, lq = lane >> 4;

    float v[8];
    if (wid < 2048) {                        // ---- x bricks ----
        int bt = wid >> 5, rem = wid & 31, nt = rem >> 2, ks = rem & 3;
        const float* s = x + (size_t)(bt*128 + nt*16 + lr) * 128 + ks*32 + lq*8;
        const float4 a = *(const float4*)s, b = *(const float4*)(s + 4);
        v[0]=a.x; v[1]=a.y; v[2]=a.z; v[3]=a.w;
        v[4]=b.x; v[5]=b.y; v[6]=b.z; v[7]=b.w;
    } else if (wid < 4096) {                 // ---- w0 bricks (masked) ----
        int u = wid - 2048, t = u >> 4, rem = u & 15, it = rem >> 2, ks = rem & 3;
        int k0 = ks*32 + lq*8;
        const float* s = w0 + (size_t)(t*64 + it*16 + lr) * 128 + k0;
        const float4 a = *(const float4*)s, b = *(const float4*)(s + 4);
        v[0]=a.x; v[1]=a.y; v[2]=a.z; v[3]=a.w;
        v[4]=b.x; v[5]=b.y; v[6]=b.z; v[7]=b.w;
        #pragma unroll
        for (int j = 0; j < 8; ++j) if (k0 + j == t) v[j] = 0.f;
    } else {                                 // ---- w1 bricks ----
        int u = wid - 4096, t = u >> 3, rem = u & 7, it = rem >> 1, ks = rem & 1;
        const float* s = w1 + (size_t)(t*64 + it*16 + lr) * 64 + ks*32 + lq*8;
        const float4 a = *(const float4*)s, b = *(const float4*)(s + 4);
        v[0]=a.x; v[1]=a.y; v[2]=a.z; v[3]=a.w;
        v[4]=b.x; v[5]=b.y; v[6]=b.z; v[7]=b.w;
    }
    union { bf16_t h[8]; uint4 q; } pk;
    #pragma unroll
    for (int j = 0; j < 8; ++j) pk.h[j] = (bf16_t)v[j];
    ((uint4*)ws)[(size_t)wid * 64 + lane] = pk.q;   // dst = brick*1024 + lane*16
}

// =========================== main fused kernel ===========================
__global__ __launch_bounds__(256, 2)
void fused_mlp(const unsigned char* __restrict__ ws,
               const float* __restrict__ w2,
               const float* __restrict__ b0, const float* __restrict__ b1,
               const float* __restrict__ b2, float* __restrict__ out)
{
    // wsm: w0 (16 KB, bricks 0..15 = it*4+ks) then w1 (8 KB, bricks 16..23 = 16+it*2+ks)
    // hsm: h bricks, 8 nt-tiles x 2 ks, wave-private slices (no barriers in loop).
    __shared__ __align__(16) unsigned char wsm[24576];
    __shared__ __align__(16) unsigned char hsm[16384];

    const int tid  = threadIdx.x;
    const int w    = tid >> 6;         // wave 0..3: owns batch rows w*32 .. w*32+31
    const int lane = tid & 63;
    const int lr = lane & 15, lq = lane >> 4;
    const int g  = blockIdx.x;         // batch super-group: bt = g*16 + s
    const int t  = blockIdx.y;         // variable index

    // ---- stage w0+w1 bricks into LDS once (24 KB, 6 x uint4 per thread) ----
    {
        const unsigned char* w0g = ws + W0B_OFF + (size_t)t*16384;
        const unsigned char* w1g = ws + W1B_OFF + (size_t)t*8192;
        #pragma unroll
        for (int j = 0; j < 6; ++j) {
            const int off = (j*256 + tid) * 16;      // 0..24560, j<4 -> w0
            uint4 v = (j < 4) ? *(const uint4*)(w0g + off)
                              : *(const uint4*)(w1g + (off - 16384));
            *(uint4*)(wsm + off) = v;
        }
    }

    // ---- w2 as fp32, per-lane slice for the in-register L2 finish ----
    f32x4 w2q[2][4];
    #pragma unroll
    for (int o = 0; o < 2; ++o)
        #pragma unroll
        for (int it = 0; it < 4; ++it)
            w2q[o][it] = *(const f32x4*)(w2 + t*128 + o*64 + it*16 + lq*4);

    // ---- biases: per-quad float4 (acc-init form) ----
    f32x4 b0q[4], b1q[4];
    #pragma unroll
    for (int it = 0; it < 4; ++it) {
        b0q[it] = *(const f32x4*)(b0 + t*64 + it*16 + lq*4);
        b1q[it] = *(const f32x4*)(b1 + t*64 + it*16 + lq*4);
    }
    const float2 b2v = *(const float2*)(b2 + t*2);

    // ---- x fragment pointer helper; preload iter 0 ----
    const unsigned char* xp = ws + XB_OFF + lane*16;
    bf16x8 xf[2][4];
    {
        const int bt0 = g*16;
        #pragma unroll
        for (int ntl = 0; ntl < 2; ++ntl)
            #pragma unroll
            for (int ks = 0; ks < 4; ++ks)
                xf[ntl][ks] = *(const bf16x8*)(xp + (size_t)(((bt0*8 + w*2+ntl)*4 + ks))*1024);
    }

    // per-lane LDS fragment bases
    const unsigned char* w0s = wsm + lane*16;           // + (it*4+ks)*1024
    const unsigned char* w1s = wsm + 16384 + lane*16;   // + (it*2+ks)*1024

    __syncthreads();   // weights staged

    for (int s = 0; s < 16; ++s) {
        const int bt = g*16 + s;

        // ============ layer 0: D0[i][row] = w0m @ x^T (+b0 via C-init) ============
        f32x4 acc0[2][4];
        #pragma unroll
        for (int ntl = 0; ntl < 2; ++ntl)
            #pragma unroll
            for (int it = 0; it < 4; ++it) acc0[ntl][it] = b0q[it];

        #pragma unroll
        for (int ks = 0; ks < 4; ++ks)
            #pragma unroll
            for (int it = 0; it < 4; ++it) {
                const bf16x8 wf = *(const bf16x8*)(w0s + (it*4+ks)*1024);
                #pragma unroll
                for (int ntl = 0; ntl < 2; ++ntl)
                    acc0[ntl][it] = __builtin_amdgcn_mfma_f32_16x16x32_bf16(
                                        wf, xf[ntl][ks], acc0[ntl][it], 0, 0, 0);
            }

        // ---- xf now dead: prefetch next iter's fragments into the same regs ----
        {
            const int btn = (s < 15) ? bt + 1 : bt;
            #pragma unroll
            for (int ntl = 0; ntl < 2; ++ntl)
                #pragma unroll
                for (int ks = 0; ks < 4; ++ks)
                    xf[ntl][ks] = *(const bf16x8*)(xp + (size_t)(((btn*8 + w*2+ntl)*4 + ks))*1024);
        }

        // epi0 -> h bricks: C reg r is k = it*16 + lq*4 + r (4 consecutive k) -> one b64
        #pragma unroll
        for (int ntl = 0; ntl < 2; ++ntl)
            #pragma unroll
            for (int it = 0; it < 4; ++it) {
                union { bf16_t h[4]; unsigned long long u; } pk;
                #pragma unroll
                for (int r = 0; r < 4; ++r) {
                    float u = acc0[ntl][it][r];
                    pk.h[r] = (bf16_t)fmaxf(u, LEAKY * u);
                }
                int off = ((w*2+ntl)*2 + (it>>1)) * 1024
                        + (((it&1)*2 + (lq>>1))*16 + lr) * 16 + (lq&1)*8;
                *(unsigned long long*)(hsm + off) = pk.u;
            }

        // ============ layers 1+2, per-ntl (halves acc1 register pressure) ============
        #pragma unroll
        for (int ntl = 0; ntl < 2; ++ntl) {
            bf16x8 hf[2];
            #pragma unroll
            for (int ks = 0; ks < 2; ++ks)
                hf[ks] = *(const bf16x8*)(hsm + ((w*2+ntl)*2 + ks)*1024 + lane*16);

            f32x4 acc1[4];
            #pragma unroll
            for (int it = 0; it < 4; ++it) acc1[it] = b1q[it];

            #pragma unroll
            for (int ks = 0; ks < 2; ++ks)
                #pragma unroll
                for (int it = 0; it < 4; ++it) {
                    const bf16x8 wf = *(const bf16x8*)(w1s + (it*2+ks)*1024);
                    acc1[it] = __builtin_amdgcn_mfma_f32_16x16x32_bf16(
                                   wf, hf[ks], acc1[it], 0, 0, 0);
                }

            // layer 2 (o=2) — in-register VALU finish:
            // out[o][row] = sum_i2 w2[o][i2] * leaky(acc1[i2][row]) + b2[o]
            float p0 = 0.f, p1 = 0.f;
            #pragma unroll
            for (int it = 0; it < 4; ++it)
                #pragma unroll
                for (int r = 0; r < 4; ++r) {
                    float u = acc1[it][r];
                    float a = fmaxf(u, LEAKY * u);
                    p0 = fmaf(w2q[0][it][r], a, p0);
                    p1 = fmaf(w2q[1][it][r], a, p1);
                }
            p0 += __shfl_xor(p0, 16); p0 += __shfl_xor(p0, 32);
            p1 += __shfl_xor(p1, 16); p1 += __shfl_xor(p1, 32);
            if (lq == 0) {
                int row = bt*128 + (w*2+ntl)*16 + lr;
                float2 o2 = { p0 + b2v.x, p1 + b2v.y };
                *(float2*)(out + (size_t)row*256 + t*2) = o2;
            }
        }
    }
}

extern "C" void kernel_launch(void* const* d_in, const int* in_sizes, int n_in,
                              void* d_out, int out_size, void* d_ws, size_t ws_size,
                              hipStream_t stream) {
    const float* x  = (const float*)d_in[0];
    const float* w0 = (const float*)d_in[1];
    const float* w1 = (const float*)d_in[2];
    const float* w2 = (const float*)d_in[3];
    const float* b0 = (const float*)d_in[4];
    const float* b1 = (const float*)d_in[5];
    const float* b2 = (const float*)d_in[6];
    unsigned char* ws = (unsigned char*)d_ws;   // needs 5120 KiB
    float* out = (float*)d_out;

    brickify<<<dim3(1280), dim3(256), 0, stream>>>(x, w0, w1, ws);
    // grid (4 super-groups, 128 t): 512 blocks = one 2-block/CU round (A/B vs R6;
    // only change this round is the weight source L2 -> LDS).
    fused_mlp<<<dim3(4, 128), dim3(256), 0, stream>>>(ws, w2, b0, b1, b2, out);
}

// Round 6
// 106.460 us; speedup vs baseline: 2.9298x; 1.0135x over previous
//
#include <hip/hip_runtime.h>

// BaseModel_3100966387783 — per-variable masked 3-layer MLP, b=8192, D=128, h=64, o=2.
//
// R9: register-resident weights via pressure diet + unroll-1 loop.
//   R8 counters: VGPR=120, MfmaUtil 22.7%, VALUBusy 40.4%, fused 42.7us flat
//   vs R6 -> weight stream just moved L2->LDS pipe (36 DS ops/iter ~= 23us of
//   DS-pipe time per CU). Root cause across R3-R8: design wants ~270 VGPR,
//   compiler rematerializes weight loads every iter. Fix: fit under 256 regs
//   (launch_bounds(256,2) -> 8 waves/CU unchanged at VGPR<=256):
//     - w0f/w1f read ONCE from LDS into regs before the loop (LDS copy kept
//       as cheap fallback if the allocator sinks the reads = R8 behavior)
//     - #pragma unroll 1 on the s-loop (compact body, stable regalloc)
//   Prediction: VGPR ~230-256, fused 42.7 -> 24-32us, dur 107.9 -> 88-97,
//   MfmaUtil -> 33-42%. If VGPR stays ~120/flat: compiler refused -> disasm.
//
// R8 (107.9 us): weights L2->LDS staging; flat vs R6 (pipe swap, not a cut).
// R7 (311.9 us): launch_bounds(256,4) -> 64 VGPR scratch-spill disaster.
// R6 (109.7 us): VGPR=120 discovery; per-ntl L1+finish split.
// R5 (107.9 us): layer-2 as in-register VALU finish.
// R3/R4 (105.7-107.4 us): brick layout, 0 barriers.
//   brick = 1 KB = 64 lanes x 16 B bf16; lane l holds
//   T[tile*16 + (l&15)][ks*32 + (l>>4)*8 + 0..7] = one MFMA A/B fragment.

typedef __bf16 bf16_t;
typedef __bf16 bf16x8 __attribute__((ext_vector_type(8)));
typedef float  f32x4  __attribute__((ext_vector_type(4)));

#define LEAKY 0.01f

// ---------------- ws brick regions (byte offsets) ----------------
#define XB_OFF   0u                  // x bricks:   64 bt x 8 nt x 4 ks = 2048 bricks
#define W0B_OFF  (2048u*1024u)       // w0 masked: 128 t x 4 it x 4 ks = 2048
#define W1B_OFF  (4096u*1024u)       // w1:        128 t x 4 it x 2 ks = 1024
// total ws need: 5120 KiB (w2 read as fp32 directly in fused_mlp)

// =================== pre-kernel: fp32 -> bf16 brick-ify ===================
__global__ __launch_bounds__(256)
void brickify(const float* __restrict__ x,  const float* __restrict__ w0,
              const float* __restrict__ w1, unsigned char* __restrict__ ws)
{
    const int wid  = blockIdx.x * 4 + (threadIdx.x >> 6);  // one wave = one brick
    const int lane = threadIdx.x & 63;
    const int lr = lane & 15, lq = lane >> 4;

    float v[8];
    if (wid < 2048) {                        // ---- x bricks ----
        int bt = wid >> 5, rem = wid & 31, nt = rem >> 2, ks = rem & 3;
        const float* s = x + (size_t)(bt*128 + nt*16 + lr) * 128 + ks*32 + lq*8;
        const float4 a = *(const float4*)s, b = *(const float4*)(s + 4);
        v[0]=a.x; v[1]=a.y; v[2]=a.z; v[3]=a.w;
        v[4]=b.x; v[5]=b.y; v[6]=b.z; v[7]=b.w;
    } else if (wid < 4096) {                 // ---- w0 bricks (masked) ----
        int u = wid - 2048, t = u >> 4, rem = u & 15, it = rem >> 2, ks = rem & 3;
        int k0 = ks*32 + lq*8;
        const float* s = w0 + (size_t)(t*64 + it*16 + lr) * 128 + k0;
        const float4 a = *(const float4*)s, b = *(const float4*)(s + 4);
        v[0]=a.x; v[1]=a.y; v[2]=a.z; v[3]=a.w;
        v[4]=b.x; v[5]=b.y; v[6]=b.z; v[7]=b.w;
        #pragma unroll
        for (int j = 0; j < 8; ++j) if (k0 + j == t) v[j] = 0.f;
    } else {                                 // ---- w1 bricks ----
        int u = wid - 4096, t = u >> 3, rem = u & 7, it = rem >> 1, ks = rem & 1;
        const float* s = w1 + (size_t)(t*64 + it*16 + lr) * 64 + ks*32 + lq*8;
        const float4 a = *(const float4*)s, b = *(const float4*)(s + 4);
        v[0]=a.x; v[1]=a.y; v[2]=a.z; v[3]=a.w;
        v[4]=b.x; v[5]=b.y; v[6]=b.z; v[7]=b.w;
    }
    union { bf16_t h[8]; uint4 q; } pk;
    #pragma unroll
    for (int j = 0; j < 8; ++j) pk.h[j] = (bf16_t)v[j];
    ((uint4*)ws)[(size_t)wid * 64 + lane] = pk.q;   // dst = brick*1024 + lane*16
}

// =========================== main fused kernel ===========================
__global__ __launch_bounds__(256, 2)
void fused_mlp(const unsigned char* __restrict__ ws,
               const float* __restrict__ w2,
               const float* __restrict__ b0, const float* __restrict__ b1,
               const float* __restrict__ b2, float* __restrict__ out)
{
    // wsm: w0 (16 KB) + w1 (8 KB) staged once; hsm: h bricks, wave-private.
    __shared__ __align__(16) unsigned char wsm[24576];
    __shared__ __align__(16) unsigned char hsm[16384];

    const int tid  = threadIdx.x;
    const int w    = tid >> 6;         // wave 0..3: owns batch rows w*32 .. w*32+31
    const int lane = tid & 63;
    const int lr = lane & 15, lq = lane >> 4;
    const int g  = blockIdx.x;         // batch super-group: bt = g*16 + s
    const int t  = blockIdx.y;         // variable index

    // ---- stage w0+w1 bricks into LDS (24 KB, 6 x uint4 per thread) ----
    {
        const unsigned char* w0g = ws + W0B_OFF + (size_t)t*16384;
        const unsigned char* w1g = ws + W1B_OFF + (size_t)t*8192;
        #pragma unroll
        for (int j = 0; j < 6; ++j) {
            const int off = (j*256 + tid) * 16;      // 0..24560, j<4 -> w0
            uint4 v = (j < 4) ? *(const uint4*)(w0g + off)
                              : *(const uint4*)(w1g + (off - 16384));
            *(uint4*)(wsm + off) = v;
        }
    }

    // ---- w2 as fp32, per-lane slice for the in-register L2 finish ----
    f32x4 w2q[2][4];
    #pragma unroll
    for (int o = 0; o < 2; ++o)
        #pragma unroll
        for (int it = 0; it < 4; ++it)
            w2q[o][it] = *(const f32x4*)(w2 + t*128 + o*64 + it*16 + lq*4);

    // ---- biases: per-quad float4 (acc-init form) ----
    f32x4 b0q[4], b1q[4];
    #pragma unroll
    for (int it = 0; it < 4; ++it) {
        b0q[it] = *(const f32x4*)(b0 + t*64 + it*16 + lq*4);
        b1q[it] = *(const f32x4*)(b1 + t*64 + it*16 + lq*4);
    }
    const float2 b2v = *(const float2*)(b2 + t*2);

    // ---- x fragment pointer helper; preload iter 0 ----
    const unsigned char* xp = ws + XB_OFF + lane*16;
    bf16x8 xf[2][4];
    {
        const int bt0 = g*16;
        #pragma unroll
        for (int ntl = 0; ntl < 2; ++ntl)
            #pragma unroll
            for (int ks = 0; ks < 4; ++ks)
                xf[ntl][ks] = *(const bf16x8*)(xp + (size_t)(((bt0*8 + w*2+ntl)*4 + ks))*1024);
    }

    __syncthreads();   // weights staged

    // ---- weights: LDS -> registers ONCE (the point of this round) ----
    bf16x8 w0f[4][4], w1f[4][2];
    {
        const unsigned char* w0s = wsm + lane*16;
        const unsigned char* w1s = wsm + 16384 + lane*16;
        #pragma unroll
        for (int it = 0; it < 4; ++it)
            #pragma unroll
            for (int ks = 0; ks < 4; ++ks)
                w0f[it][ks] = *(const bf16x8*)(w0s + (it*4+ks)*1024);
        #pragma unroll
        for (int it = 0; it < 4; ++it)
            #pragma unroll
            for (int ks = 0; ks < 2; ++ks)
                w1f[it][ks] = *(const bf16x8*)(w1s + (it*2+ks)*1024);
    }

    #pragma unroll 1   // keep ONE compact body: stable regalloc, no remat blob
    for (int s = 0; s < 16; ++s) {
        const int bt = g*16 + s;

        // ============ layer 0: D0[i][row] = w0m @ x^T (+b0 via C-init) ============
        f32x4 acc0[2][4];
        #pragma unroll
        for (int ntl = 0; ntl < 2; ++ntl)
            #pragma unroll
            for (int it = 0; it < 4; ++it) acc0[ntl][it] = b0q[it];

        #pragma unroll
        for (int ks = 0; ks < 4; ++ks)
            #pragma unroll
            for (int it = 0; it < 4; ++it)
                #pragma unroll
                for (int ntl = 0; ntl < 2; ++ntl)
                    acc0[ntl][it] = __builtin_amdgcn_mfma_f32_16x16x32_bf16(
                                        w0f[it][ks], xf[ntl][ks], acc0[ntl][it], 0, 0, 0);

        // ---- xf now dead: prefetch next iter's fragments into the same regs ----
        {
            const int btn = (s < 15) ? bt + 1 : bt;
            #pragma unroll
            for (int ntl = 0; ntl < 2; ++ntl)
                #pragma unroll
                for (int ks = 0; ks < 4; ++ks)
                    xf[ntl][ks] = *(const bf16x8*)(xp + (size_t)(((btn*8 + w*2+ntl)*4 + ks))*1024);
        }

        // epi0 -> h bricks: C reg r is k = it*16 + lq*4 + r (4 consecutive k) -> one b64
        #pragma unroll
        for (int ntl = 0; ntl < 2; ++ntl)
            #pragma unroll
            for (int it = 0; it < 4; ++it) {
                union { bf16_t h[4]; unsigned long long u; } pk;
                #pragma unroll
                for (int r = 0; r < 4; ++r) {
                    float u = acc0[ntl][it][r];
                    pk.h[r] = (bf16_t)fmaxf(u, LEAKY * u);
                }
                int off = ((w*2+ntl)*2 + (it>>1)) * 1024
                        + (((it&1)*2 + (lq>>1))*16 + lr) * 16 + (lq&1)*8;
                *(unsigned long long*)(hsm + off) = pk.u;
            }

        // ============ layers 1+2, per-ntl (keeps acc1 at 16 regs) ============
        #pragma unroll
        for (int ntl = 0; ntl < 2; ++ntl) {
            bf16x8 hf[2];
            #pragma unroll
            for (int ks = 0; ks < 2; ++ks)
                hf[ks] = *(const bf16x8*)(hsm + ((w*2+ntl)*2 + ks)*1024 + lane*16);

            f32x4 acc1[4];
            #pragma unroll
            for (int it = 0; it < 4; ++it) acc1[it] = b1q[it];

            #pragma unroll
            for (int ks = 0; ks < 2; ++ks)
                #pragma unroll
                for (int it = 0; it < 4; ++it)
                    acc1[it] = __builtin_amdgcn_mfma_f32_16x16x32_bf16(
                                   w1f[it][ks], hf[ks], acc1[it], 0, 0, 0);

            // layer 2 (o=2) — in-register VALU finish:
            // out[o][row] = sum_i2 w2[o][i2] * leaky(acc1[i2][row]) + b2[o]
            float p0 = 0.f, p1 = 0.f;
            #pragma unroll
            for (int it = 0; it < 4; ++it)
                #pragma unroll
                for (int r = 0; r < 4; ++r) {
                    float u = acc1[it][r];
                    float a = fmaxf(u, LEAKY * u);
                    p0 = fmaf(w2q[0][it][r], a, p0);
                    p1 = fmaf(w2q[1][it][r], a, p1);
                }
            p0 += __shfl_xor(p0, 16); p0 += __shfl_xor(p0, 32);
            p1 += __shfl_xor(p1, 16); p1 += __shfl_xor(p1, 32);
            if (lq == 0) {
                int row = bt*128 + (w*2+ntl)*16 + lr;
                float2 o2 = { p0 + b2v.x, p1 + b2v.y };
                *(float2*)(out + (size_t)row*256 + t*2) = o2;
            }
        }
    }
}

extern "C" void kernel_launch(void* const* d_in, const int* in_sizes, int n_in,
                              void* d_out, int out_size, void* d_ws, size_t ws_size,
                              hipStream_t stream) {
    const float* x  = (const float*)d_in[0];
    const float* w0 = (const float*)d_in[1];
    const float* w1 = (const float*)d_in[2];
    const float* w2 = (const float*)d_in[3];
    const float* b0 = (const float*)d_in[4];
    const float* b1 = (const float*)d_in[5];
    const float* b2 = (const float*)d_in[6];
    unsigned char* ws = (unsigned char*)d_ws;   // needs 5120 KiB
    float* out = (float*)d_out;

    brickify<<<dim3(1280), dim3(256), 0, stream>>>(x, w0, w1, ws);
    // grid (4 super-groups, 128 t): 512 blocks = 2 blocks/CU = 8 waves/CU,
    // which is exactly the max at VGPR<=256 — resident-weight plan loses
    // no occupancy vs R6/R8.
    fused_mlp<<<dim3(4, 128), dim3(256), 0, stream>>>(ws, w2, b0, b1, b2, out);
}